// Round 1
// baseline (551.877 us; speedup 1.0000x reference)
//
#include <hip/hip_runtime.h>
#include <cstdint>
#include <cstddef>

// Problem constants (fixed by the reference)
#define N_NODES 10000
#define F_IN    512
#define NHID    32
#define LATENT  16

// ---------------------------------------------------------------------------
// GEMM1: h0 = x @ W1   [10000,512] x [512,32] -> [10000,32]
// block = 256 threads = 8 rows x 32 cols; x rows staged in LDS.
// ---------------------------------------------------------------------------
__global__ __launch_bounds__(256) void gemm1_kernel(const float* __restrict__ x,
                                                    const float* __restrict__ W1,
                                                    float* __restrict__ h0) {
    __shared__ float xs[8][F_IN];  // 16 KB
    const int row0 = blockIdx.x * 8;
    // cooperative coalesced load of 8 rows x 512 floats
    for (int t = threadIdx.x; t < 8 * F_IN; t += 256) {
        const int r = t >> 9;          // /512
        const int c = t & (F_IN - 1);  // %512
        if (row0 + r < N_NODES)
            xs[r][c] = x[(size_t)(row0 + r) * F_IN + c];
    }
    __syncthreads();

    const int col = threadIdx.x & 31;
    const int r   = threadIdx.x >> 5;
    if (row0 + r < N_NODES) {
        float acc = 0.f;
#pragma unroll 8
        for (int k = 0; k < F_IN; ++k) {
            acc += xs[r][k] * W1[k * NHID + col];
        }
        h0[(size_t)(row0 + r) * NHID + col] = acc;
    }
}

// ---------------------------------------------------------------------------
// CSR build — step 1: degree histogram over dst.
// ---------------------------------------------------------------------------
__global__ __launch_bounds__(256) void hist_kernel(const int* __restrict__ dst,
                                                   int* __restrict__ deg, int E) {
    const int e = blockIdx.x * 256 + threadIdx.x;
    if (e < E) atomicAdd(&deg[dst[e]], 1);
}

// ---------------------------------------------------------------------------
// CSR build — step 2: single-block exclusive scan of deg[0..N) -> off, cursor.
// 256 threads x 40-element chunks; Hillis-Steele scan of the 256 partials.
// ---------------------------------------------------------------------------
#define SCAN_T  256
#define CHUNK   40   // ceil(10000/256)

__global__ __launch_bounds__(SCAN_T) void scan_kernel(const int* __restrict__ deg,
                                                      int* __restrict__ off,
                                                      int* __restrict__ cursor) {
    __shared__ int part[SCAN_T];
    const int t  = threadIdx.x;
    const int i0 = t * CHUNK;

    int s = 0;
    for (int i = 0; i < CHUNK; ++i) {
        const int idx = i0 + i;
        if (idx < N_NODES) s += deg[idx];
    }
    part[t] = s;
    __syncthreads();

    // inclusive scan of partials
    for (int d = 1; d < SCAN_T; d <<= 1) {
        int w = (t >= d) ? part[t - d] : 0;
        __syncthreads();
        part[t] += w;
        __syncthreads();
    }

    int run = part[t] - s;  // exclusive prefix of this thread's chunk
    for (int i = 0; i < CHUNK; ++i) {
        const int idx = i0 + i;
        if (idx < N_NODES) {
            off[idx]    = run;
            cursor[idx] = run;
            run += deg[idx];
        }
    }
    if (t == SCAN_T - 1) off[N_NODES] = run;  // = E
}

// ---------------------------------------------------------------------------
// CSR build — step 3: scatter edges into packed (src, bitcast(w)) slots.
// ---------------------------------------------------------------------------
__global__ __launch_bounds__(256) void scatter_kernel(const int* __restrict__ src,
                                                      const int* __restrict__ dst,
                                                      const float* __restrict__ w,
                                                      int* __restrict__ cursor,
                                                      int2* __restrict__ csr, int E) {
    const int e = blockIdx.x * 256 + threadIdx.x;
    if (e < E) {
        const int pos = atomicAdd(&cursor[dst[e]], 1);
        csr[pos] = make_int2(src[e], __float_as_int(w[e]));
    }
}

// ---------------------------------------------------------------------------
// Gather-SpMM: hout[i][d] = sum over CSR row i of w * hin[src][d].
// One wave per destination node; lane = (edge-sub-slot, feature d).
// 64/D edges processed per iteration; cross-sub reduce via shfl_xor.
// Zero atomics; one plain store per output element.
// ---------------------------------------------------------------------------
template <int D>
__global__ __launch_bounds__(256) void spmm_gather(const int* __restrict__ off,
                                                   const int2* __restrict__ csr,
                                                   const float* __restrict__ hin,
                                                   float* __restrict__ hout) {
    constexpr int EPI  = 64 / D;             // edges per iteration
    constexpr int LOGD = (D == 32) ? 5 : 4;
    const int wid  = (blockIdx.x * 256 + threadIdx.x) >> 6;  // node = global wave id
    const int lane = threadIdx.x & 63;
    if (wid >= N_NODES) return;

    const int d   = lane & (D - 1);
    const int sub = lane >> LOGD;
    const int p1  = off[wid + 1];

    float acc = 0.f;
    for (int p = off[wid] + sub; p < p1; p += EPI) {
        const int2 sw = csr[p];              // broadcast within sub-group
        acc += __int_as_float(sw.y) * hin[(size_t)sw.x * D + d];  // coalesced gather
    }
#pragma unroll
    for (int m = D; m < 64; m <<= 1) acc += __shfl_xor(acc, m);

    if (lane < D) hout[(size_t)wid * D + d] = acc;
}

// ---------------------------------------------------------------------------
// GEMM2: z0 = h @ W2   [10000,32] x [32,16] -> [10000,16]
// one thread per output element; W2 (512 floats) staged in LDS.
// ---------------------------------------------------------------------------
__global__ __launch_bounds__(256) void gemm2_kernel(const float* __restrict__ h,
                                                    const float* __restrict__ W2,
                                                    float* __restrict__ z0) {
    __shared__ float w2s[NHID * LATENT];
    for (int t = threadIdx.x; t < NHID * LATENT; t += 256) w2s[t] = W2[t];
    __syncthreads();

    const int idx = blockIdx.x * 256 + threadIdx.x;
    if (idx < N_NODES * LATENT) {
        const int row = idx >> 4;            // / LATENT
        const int col = idx & (LATENT - 1);  // % LATENT
        const float* __restrict__ hr = h + (size_t)row * NHID;
        float acc = 0.f;
#pragma unroll
        for (int k = 0; k < NHID; ++k) acc += hr[k] * w2s[k * LATENT + col];
        z0[idx] = acc;
    }
}

// ---------------------------------------------------------------------------
// Decoder: out[i][j] = sigmoid(dot(z[i], z[j])), N x N output.
// block = 256 threads, each owning one column j (z[j] in 16 VGPRs).
// z[i] loads are wave-uniform -> scalarized; write-BW bound (~63 us floor).
// ---------------------------------------------------------------------------
#define TI 32

__device__ __forceinline__ float sigmoid_fast(float x) {
    return __builtin_amdgcn_rcpf(1.0f + __expf(-x));
}

__global__ __launch_bounds__(256) void decoder_kernel(const float* __restrict__ z,
                                                      float* __restrict__ out) {
    const int j  = blockIdx.x * 256 + threadIdx.x;
    const int i0 = blockIdx.y * TI;

    float4 zj0, zj1, zj2, zj3;
    if (j < N_NODES) {
        const float4* __restrict__ zp = (const float4*)(z + (size_t)j * LATENT);
        zj0 = zp[0]; zj1 = zp[1]; zj2 = zp[2]; zj3 = zp[3];
    } else {
        zj0 = zj1 = zj2 = zj3 = make_float4(0.f, 0.f, 0.f, 0.f);
    }

    const int imax = min(TI, N_NODES - i0);
    if (imax == TI) {
#pragma unroll 4
        for (int ii = 0; ii < TI; ++ii) {
            const float4* __restrict__ zi = (const float4*)(z + (size_t)(i0 + ii) * LATENT);
            const float4 a0 = zi[0], a1 = zi[1], a2 = zi[2], a3 = zi[3];
            float acc = a0.x * zj0.x + a0.y * zj0.y + a0.z * zj0.z + a0.w * zj0.w
                      + a1.x * zj1.x + a1.y * zj1.y + a1.z * zj1.z + a1.w * zj1.w
                      + a2.x * zj2.x + a2.y * zj2.y + a2.z * zj2.z + a2.w * zj2.w
                      + a3.x * zj3.x + a3.y * zj3.y + a3.z * zj3.z + a3.w * zj3.w;
            if (j < N_NODES) {
                __builtin_nontemporal_store(sigmoid_fast(acc),
                                            &out[(size_t)(i0 + ii) * N_NODES + j]);
            }
        }
    } else {
        for (int ii = 0; ii < imax; ++ii) {
            const float4* __restrict__ zi = (const float4*)(z + (size_t)(i0 + ii) * LATENT);
            const float4 a0 = zi[0], a1 = zi[1], a2 = zi[2], a3 = zi[3];
            float acc = a0.x * zj0.x + a0.y * zj0.y + a0.z * zj0.z + a0.w * zj0.w
                      + a1.x * zj1.x + a1.y * zj1.y + a1.z * zj1.z + a1.w * zj1.w
                      + a2.x * zj2.x + a2.y * zj2.y + a2.z * zj2.z + a2.w * zj2.w
                      + a3.x * zj3.x + a3.y * zj3.y + a3.z * zj3.z + a3.w * zj3.w;
            if (j < N_NODES) {
                __builtin_nontemporal_store(sigmoid_fast(acc),
                                            &out[(size_t)(i0 + ii) * N_NODES + j]);
            }
        }
    }
}

// ---------------------------------------------------------------------------
// Launch: scratch (h0, h, z0, CSR) lives inside the adj-recon region of
// d_out, which the decoder fully overwrites last. z accumulates directly
// into its final spot (tail of d_out). No atomics in the SpMM accumulate:
// CSR is built once (histogram + scan + scatter) and reused by both layers.
// ---------------------------------------------------------------------------
extern "C" void kernel_launch(void* const* d_in, const int* in_sizes, int n_in,
                              void* d_out, int out_size, void* d_ws, size_t ws_size,
                              hipStream_t stream) {
    const float* x  = (const float*)d_in[0];   // [N, 512]
    const float* W1 = (const float*)d_in[1];   // [512, 32]
    const float* W2 = (const float*)d_in[2];   // [32, 16]
    const int*   ei = (const int*)d_in[3];     // [2, E]
    const float* ew = (const float*)d_in[4];   // [E]
    const int E = in_sizes[3] / 2;
    const int* src = ei;
    const int* dst = ei + E;

    float* out = (float*)d_out;                              // [N, N]
    float* z   = out + (size_t)N_NODES * N_NODES;            // [N, 16] (final tail)

    // scratch inside the adj region (overwritten by decoder at the end)
    float* h0 = out;                              // N*32 floats        @ 0
    float* h  = h0 + N_NODES * NHID;              // N*32 floats        @ 320000
    float* z0 = h  + N_NODES * NHID;              // N*16 floats        @ 640000
    int*   deg    = (int*)(z0 + N_NODES * LATENT);   // N+1 ints        @ 800000
    int*   off    = deg;                             // reuse: hist then scan writes off
    int*   cursor = deg + (N_NODES + 16);            // N ints          @ 810016 (hist deg kept separate below)
    int2*  csr    = (int2*)(cursor + (N_NODES + 16));// E int2          @ 820032 (8B aligned)

    // NOTE: deg and off share storage is NOT safe (scan reads deg, writes off
    // in-place per element AFTER reading it within the same thread's chunk --
    // off[idx] is written before deg[idx] is re-read only within one thread,
    // and each element is touched by exactly one thread, with the read of
    // deg[idx] happening after the write of off[idx]). To keep it obviously
    // correct, give them separate arrays:
    int* deg_arr = deg;                                  // [N]
    int* off_arr = (int*)(csr) + 2 * 320000;             // [N+1] placed after csr
    // (E is fixed at 320000 by the problem; csr sized for it above)

    // 1) degree histogram
    hipMemsetAsync(deg_arr, 0, (size_t)N_NODES * sizeof(int), stream);
    hist_kernel<<<(E + 255) / 256, 256, 0, stream>>>(dst, deg_arr, E);

    // 2) exclusive scan -> off, cursor
    scan_kernel<<<1, SCAN_T, 0, stream>>>(deg_arr, off_arr, cursor);

    // 3) scatter edges into CSR slots
    scatter_kernel<<<(E + 255) / 256, 256, 0, stream>>>(src, dst, ew, cursor, csr, E);

    // layer 1: h0 = x @ W1 ; h = A @ h0
    gemm1_kernel<<<(N_NODES + 7) / 8, 256, 0, stream>>>(x, W1, h0);
    spmm_gather<NHID><<<(N_NODES * 64 + 255) / 256, 256, 0, stream>>>(off_arr, csr, h0, h);

    // layer 2: z0 = h @ W2 ; z = A @ z0
    gemm2_kernel<<<(N_NODES * LATENT + 255) / 256, 256, 0, stream>>>(h, W2, z0);
    spmm_gather<LATENT><<<(N_NODES * 64 + 255) / 256, 256, 0, stream>>>(off_arr, csr, z0, z);

    // decoder: adj_recon = sigmoid(z @ z^T)
    dim3 dgrid((N_NODES + 255) / 256, (N_NODES + TI - 1) / TI);
    decoder_kernel<<<dgrid, 256, 0, stream>>>(z, out);
}

// Round 3
// 502.696 us; speedup vs baseline: 1.0978x; 1.0978x over previous
//
#include <hip/hip_runtime.h>
#include <cstdint>
#include <cstddef>

// Problem constants (fixed by the reference)
#define N_NODES 10000
#define F_IN    512
#define NHID    32
#define LATENT  16

// native vector type (accepted by __builtin_nontemporal_store; HIP's float4
// is a class and gets rejected)
typedef float v4f __attribute__((ext_vector_type(4)));

// ---------------------------------------------------------------------------
// GEMM1: h0 = x @ W1   [10000,512] x [512,32] -> [10000,32]
// block = 256 threads = 8 rows x 32 cols; x rows staged in LDS.
// Also zero-initializes the two atomic accumulators (h: 320k floats,
// z: 160k floats) -- grid is exactly 320k threads, saves 2 memset dispatches.
// 4 partial accumulators + float4 LDS reads break the serial FMA chain.
// ---------------------------------------------------------------------------
__global__ __launch_bounds__(256) void gemm1_kernel(const float* __restrict__ x,
                                                    const float* __restrict__ W1,
                                                    float* __restrict__ h0,
                                                    float* __restrict__ h,
                                                    float* __restrict__ z) {
    const int gid = blockIdx.x * 256 + threadIdx.x;  // 1250*256 = 320000 exactly
    h[gid] = 0.f;                                    // zero layer-1 accumulator
    if (gid < N_NODES * LATENT) z[gid] = 0.f;        // zero layer-2 accumulator

    __shared__ float xs[8][F_IN];  // 16 KB
    const int row0 = blockIdx.x * 8;  // 1250 blocks x 8 rows = 10000 exactly
    for (int t = threadIdx.x; t < 8 * F_IN; t += 256) {
        const int r = t >> 9;          // /512
        const int c = t & (F_IN - 1);  // %512
        xs[r][c] = x[(size_t)(row0 + r) * F_IN + c];
    }
    __syncthreads();

    const int col = threadIdx.x & 31;
    const int r   = threadIdx.x >> 5;
    float a0 = 0.f, a1 = 0.f, a2 = 0.f, a3 = 0.f;
#pragma unroll 4
    for (int k = 0; k < F_IN; k += 4) {
        const float4 xv = *(const float4*)&xs[r][k];  // ds_read_b128, broadcast
        a0 += xv.x * W1[(k + 0) * NHID + col];
        a1 += xv.y * W1[(k + 1) * NHID + col];
        a2 += xv.z * W1[(k + 2) * NHID + col];
        a3 += xv.w * W1[(k + 3) * NHID + col];
    }
    h0[(size_t)(row0 + r) * NHID + col] = (a0 + a1) + (a2 + a3);
}

// ---------------------------------------------------------------------------
// SpMM (scatter form): hout[dst[e]][d] += w[e] * hin[src[e]][d]
// one thread per (edge, feature). D is a power of two (32 or 16).
// ---------------------------------------------------------------------------
template <int D>
__global__ __launch_bounds__(256) void spmm_kernel(const int* __restrict__ src,
                                                   const int* __restrict__ dst,
                                                   const float* __restrict__ w,
                                                   const float* __restrict__ hin,
                                                   float* __restrict__ hout,
                                                   int E) {
    const int idx = blockIdx.x * 256 + threadIdx.x;
    const int e = idx / D;   // D is constexpr pow2 -> shift
    const int d = idx & (D - 1);
    if (e < E) {
        const int s = src[e];
        const int t = dst[e];
        const float val = w[e] * hin[(size_t)s * D + d];
        atomicAdd(&hout[(size_t)t * D + d], val);
    }
}

// ---------------------------------------------------------------------------
// GEMM2: z0 = h @ W2   [10000,32] x [32,16] -> [10000,16]
// one thread per output element; W2 (512 floats) staged in LDS.
// ---------------------------------------------------------------------------
__global__ __launch_bounds__(256) void gemm2_kernel(const float* __restrict__ h,
                                                    const float* __restrict__ W2,
                                                    float* __restrict__ z0) {
    __shared__ float w2s[NHID * LATENT];
    for (int t = threadIdx.x; t < NHID * LATENT; t += 256) w2s[t] = W2[t];
    __syncthreads();

    const int idx = blockIdx.x * 256 + threadIdx.x;
    if (idx < N_NODES * LATENT) {
        const int row = idx >> 4;            // / LATENT
        const int col = idx & (LATENT - 1);  // % LATENT
        const float* __restrict__ hr = h + (size_t)row * NHID;
        float acc = 0.f;
#pragma unroll
        for (int k = 0; k < NHID; ++k) acc += hr[k] * w2s[k * LATENT + col];
        z0[idx] = acc;
    }
}

// ---------------------------------------------------------------------------
// Decoder: out[i][j] = sigmoid(dot(z[i], z[j])), N x N output.
// Each thread owns FOUR consecutive columns j0..j0+3 (4x float4 of z in
// VGPRs) and stores one nontemporal dwordx4 per row -> 4x fewer store
// instructions than the scalar version; z[i] loads are block-uniform ->
// scalarized to s_load_dwordx4. Write-BW bound: 400 MB (~63 us floor).
// ---------------------------------------------------------------------------
#define TI 32

__device__ __forceinline__ float sigmoid_fast(float x) {
    return __builtin_amdgcn_rcpf(1.0f + __expf(-x));
}

__global__ __launch_bounds__(256) void decoder_kernel(const float* __restrict__ z,
                                                      float* __restrict__ out) {
    const int j0 = (blockIdx.x * 256 + threadIdx.x) << 2;  // 4 cols per thread
    const int i0 = blockIdx.y * TI;
    if (j0 >= N_NODES) return;   // N_NODES % 4 == 0, so j0..j0+3 all valid

    // 4 column vectors z[j0+q][0..15] in registers (fully unrolled -> static idx)
    float4 zj0[4], zj1[4], zj2[4], zj3[4];
    {
        const float4* zp0 = (const float4*)(z + (size_t)(j0 + 0) * LATENT);
        const float4* zp1 = (const float4*)(z + (size_t)(j0 + 1) * LATENT);
        const float4* zp2 = (const float4*)(z + (size_t)(j0 + 2) * LATENT);
        const float4* zp3 = (const float4*)(z + (size_t)(j0 + 3) * LATENT);
#pragma unroll
        for (int p = 0; p < 4; ++p) {
            zj0[p] = zp0[p]; zj1[p] = zp1[p]; zj2[p] = zp2[p]; zj3[p] = zp3[p];
        }
    }

    const int imax = min(TI, N_NODES - i0);
#pragma unroll 2
    for (int ii = 0; ii < imax; ++ii) {
        const float4* __restrict__ zi = (const float4*)(z + (size_t)(i0 + ii) * LATENT);
        const float4 a0 = zi[0], a1 = zi[1], a2 = zi[2], a3 = zi[3];  // s_loads

        v4f r;
        r.x = a0.x*zj0[0].x + a0.y*zj0[0].y + a0.z*zj0[0].z + a0.w*zj0[0].w
            + a1.x*zj0[1].x + a1.y*zj0[1].y + a1.z*zj0[1].z + a1.w*zj0[1].w
            + a2.x*zj0[2].x + a2.y*zj0[2].y + a2.z*zj0[2].z + a2.w*zj0[2].w
            + a3.x*zj0[3].x + a3.y*zj0[3].y + a3.z*zj0[3].z + a3.w*zj0[3].w;
        r.y = a0.x*zj1[0].x + a0.y*zj1[0].y + a0.z*zj1[0].z + a0.w*zj1[0].w
            + a1.x*zj1[1].x + a1.y*zj1[1].y + a1.z*zj1[1].z + a1.w*zj1[1].w
            + a2.x*zj1[2].x + a2.y*zj1[2].y + a2.z*zj1[2].z + a2.w*zj1[2].w
            + a3.x*zj1[3].x + a3.y*zj1[3].y + a3.z*zj1[3].z + a3.w*zj1[3].w;
        r.z = a0.x*zj2[0].x + a0.y*zj2[0].y + a0.z*zj2[0].z + a0.w*zj2[0].w
            + a1.x*zj2[1].x + a1.y*zj2[1].y + a1.z*zj2[1].z + a1.w*zj2[1].w
            + a2.x*zj2[2].x + a2.y*zj2[2].y + a2.z*zj2[2].z + a2.w*zj2[2].w
            + a3.x*zj2[3].x + a3.y*zj2[3].y + a3.z*zj2[3].z + a3.w*zj2[3].w;
        r.w = a0.x*zj3[0].x + a0.y*zj3[0].y + a0.z*zj3[0].z + a0.w*zj3[0].w
            + a1.x*zj3[1].x + a1.y*zj3[1].y + a1.z*zj3[1].z + a1.w*zj3[1].w
            + a2.x*zj3[2].x + a2.y*zj3[2].y + a2.z*zj3[2].z + a2.w*zj3[2].w
            + a3.x*zj3[3].x + a3.y*zj3[3].y + a3.z*zj3[3].z + a3.w*zj3[3].w;

        r.x = sigmoid_fast(r.x);
        r.y = sigmoid_fast(r.y);
        r.z = sigmoid_fast(r.z);
        r.w = sigmoid_fast(r.w);

        __builtin_nontemporal_store(
            r, (v4f*)(out + (size_t)(i0 + ii) * N_NODES + j0));
    }
}

// ---------------------------------------------------------------------------
// Launch: scratch (h0, h, z0) lives inside the adj-recon region of d_out,
// which the decoder fully overwrites last. z accumulates directly into its
// final spot (tail of d_out). Zero-init of h and z is folded into gemm1.
// 5 dispatches total.
// ---------------------------------------------------------------------------
extern "C" void kernel_launch(void* const* d_in, const int* in_sizes, int n_in,
                              void* d_out, int out_size, void* d_ws, size_t ws_size,
                              hipStream_t stream) {
    const float* x  = (const float*)d_in[0];   // [N, 512]
    const float* W1 = (const float*)d_in[1];   // [512, 32]
    const float* W2 = (const float*)d_in[2];   // [32, 16]
    const int*   ei = (const int*)d_in[3];     // [2, E]
    const float* ew = (const float*)d_in[4];   // [E]
    const int E = in_sizes[3] / 2;
    const int* src = ei;
    const int* dst = ei + E;

    float* out = (float*)d_out;                              // [N, N]
    float* z   = out + (size_t)N_NODES * N_NODES;            // [N, 16] (final tail)

    // scratch inside the adj region (overwritten by decoder at the end)
    float* h0 = out;                      // N*32 floats
    float* h  = h0 + N_NODES * NHID;      // N*32 floats
    float* z0 = h  + N_NODES * NHID;      // N*16 floats   (total 800k floats << N*N)

    // layer 1 (gemm1 also zeroes h and z)
    gemm1_kernel<<<N_NODES / 8, 256, 0, stream>>>(x, W1, h0, h, z);
    spmm_kernel<NHID><<<(E * NHID + 255) / 256, 256, 0, stream>>>(src, dst, ew, h0, h, E);

    // layer 2
    gemm2_kernel<<<(N_NODES * LATENT + 255) / 256, 256, 0, stream>>>(h, W2, z0);
    spmm_kernel<LATENT><<<(E * LATENT + 255) / 256, 256, 0, stream>>>(src, dst, ew, z0, z, E);

    // decoder: adj_recon = sigmoid(z @ z^T)
    dim3 dgrid((N_NODES / 4 + 255) / 256, (N_NODES + TI - 1) / TI);
    decoder_kernel<<<dgrid, 256, 0, stream>>>(z, out);
}

// Round 4
// 479.321 us; speedup vs baseline: 1.1514x; 1.0488x over previous
//
#include <hip/hip_runtime.h>
#include <cstdint>
#include <cstddef>

// Problem constants (fixed by the reference)
#define N_NODES 10000
#define F_IN    512
#define NHID    32
#define LATENT  16

// native vector type (accepted by __builtin_nontemporal_store; HIP's float4
// is a class and gets rejected)
typedef float v4f __attribute__((ext_vector_type(4)));

// ---------------------------------------------------------------------------
// Key algebraic identity: there is NO nonlinearity between the two GCN
// layers, so  z = A @ ((A @ (x@W1)) @ W2) = A @ (A @ (x @ (W1@W2))).
// We precompute W12 = W1@W2 (512x16) and run BOTH SpMMs at D=16:
// atomic count drops from E*(32+16)=15.36M to 2*E*16=10.24M, h is never
// materialized, and gemm2 disappears.
// ---------------------------------------------------------------------------

// W12[r][c] = sum_k W1[r][k] * W2[k][c];  512x32 @ 32x16 -> 512x16.
__global__ __launch_bounds__(256) void w12_kernel(const float* __restrict__ W1,
                                                  const float* __restrict__ W2,
                                                  float* __restrict__ W12) {
    __shared__ float w2s[NHID * LATENT];
    for (int t = threadIdx.x; t < NHID * LATENT; t += 256) w2s[t] = W2[t];
    __syncthreads();

    const int idx = blockIdx.x * 256 + threadIdx.x;  // 32 blocks * 256 = 8192
    const int r = idx >> 4;            // / LATENT
    const int c = idx & (LATENT - 1);  // % LATENT
    float acc = 0.f;
#pragma unroll
    for (int k = 0; k < NHID; ++k) acc += W1[r * NHID + k] * w2s[k * LATENT + c];
    W12[idx] = acc;  // idx == r*LATENT + c (row-major)
}

// ---------------------------------------------------------------------------
// GEMM1: g0 = x @ W12   [10000,512] x [512,16] -> [10000,16]
// block = 256 threads = 16 rows x 16 cols; x rows staged in LDS (32 KB).
// Also zero-initializes both atomic accumulators (g1, z: 160k floats each)
// -- grid is exactly 160k threads. 4 partial accumulators + float4 LDS reads.
// ---------------------------------------------------------------------------
__global__ __launch_bounds__(256) void gemm1_kernel(const float* __restrict__ x,
                                                    const float* __restrict__ W12,
                                                    float* __restrict__ g0,
                                                    float* __restrict__ g1,
                                                    float* __restrict__ z) {
    const int gid = blockIdx.x * 256 + threadIdx.x;  // 625*256 = 160000 exactly
    g1[gid] = 0.f;   // zero layer-1 accumulator (N*16 floats)
    z[gid]  = 0.f;   // zero layer-2 accumulator (N*16 floats)

    __shared__ float xs[16][F_IN];  // 32 KB
    const int row0 = blockIdx.x * 16;  // 625 blocks x 16 rows = 10000 exactly
    for (int t = threadIdx.x; t < 16 * F_IN; t += 256) {
        const int r = t >> 9;          // /512
        const int c = t & (F_IN - 1);  // %512
        xs[r][c] = x[(size_t)(row0 + r) * F_IN + c];
    }
    __syncthreads();

    const int col = threadIdx.x & 15;
    const int r   = threadIdx.x >> 4;
    float a0 = 0.f, a1 = 0.f, a2 = 0.f, a3 = 0.f;
#pragma unroll 4
    for (int k = 0; k < F_IN; k += 4) {
        const float4 xv = *(const float4*)&xs[r][k];  // ds_read_b128, broadcast
        a0 += xv.x * W12[(k + 0) * LATENT + col];
        a1 += xv.y * W12[(k + 1) * LATENT + col];
        a2 += xv.z * W12[(k + 2) * LATENT + col];
        a3 += xv.w * W12[(k + 3) * LATENT + col];
    }
    g0[(size_t)(row0 + r) * LATENT + col] = (a0 + a1) + (a2 + a3);
}

// ---------------------------------------------------------------------------
// SpMM (scatter form): hout[dst[e]][d] += w[e] * hin[src[e]][d]
// one thread per (edge, feature). D = 16 for both layers now.
// ---------------------------------------------------------------------------
template <int D>
__global__ __launch_bounds__(256) void spmm_kernel(const int* __restrict__ src,
                                                   const int* __restrict__ dst,
                                                   const float* __restrict__ w,
                                                   const float* __restrict__ hin,
                                                   float* __restrict__ hout,
                                                   int E) {
    const int idx = blockIdx.x * 256 + threadIdx.x;
    const int e = idx / D;   // D is constexpr pow2 -> shift
    const int d = idx & (D - 1);
    if (e < E) {
        const int s = src[e];
        const int t = dst[e];
        const float val = w[e] * hin[(size_t)s * D + d];
        atomicAdd(&hout[(size_t)t * D + d], val);
    }
}

// ---------------------------------------------------------------------------
// Decoder: out[i][j] = sigmoid(dot(z[i], z[j])), N x N output.
// Each thread owns FOUR consecutive columns j0..j0+3 (4x float4 of z in
// VGPRs) and stores one nontemporal dwordx4 per row; z[i] loads are
// block-uniform -> scalarized. Write-BW bound: 400 MB (~63 us floor).
// ---------------------------------------------------------------------------
#define TI 32

__device__ __forceinline__ float sigmoid_fast(float x) {
    return __builtin_amdgcn_rcpf(1.0f + __expf(-x));
}

__global__ __launch_bounds__(256) void decoder_kernel(const float* __restrict__ z,
                                                      float* __restrict__ out) {
    const int j0 = (blockIdx.x * 256 + threadIdx.x) << 2;  // 4 cols per thread
    const int i0 = blockIdx.y * TI;
    if (j0 >= N_NODES) return;   // N_NODES % 4 == 0, so j0..j0+3 all valid

    // 4 column vectors z[j0+q][0..15] in registers (fully unrolled -> static idx)
    float4 zj0[4], zj1[4], zj2[4], zj3[4];
    {
        const float4* zp0 = (const float4*)(z + (size_t)(j0 + 0) * LATENT);
        const float4* zp1 = (const float4*)(z + (size_t)(j0 + 1) * LATENT);
        const float4* zp2 = (const float4*)(z + (size_t)(j0 + 2) * LATENT);
        const float4* zp3 = (const float4*)(z + (size_t)(j0 + 3) * LATENT);
#pragma unroll
        for (int p = 0; p < 4; ++p) {
            zj0[p] = zp0[p]; zj1[p] = zp1[p]; zj2[p] = zp2[p]; zj3[p] = zp3[p];
        }
    }

    const int imax = min(TI, N_NODES - i0);
#pragma unroll 2
    for (int ii = 0; ii < imax; ++ii) {
        const float4* __restrict__ zi = (const float4*)(z + (size_t)(i0 + ii) * LATENT);
        const float4 a0 = zi[0], a1 = zi[1], a2 = zi[2], a3 = zi[3];  // s_loads

        v4f r;
        r.x = a0.x*zj0[0].x + a0.y*zj0[0].y + a0.z*zj0[0].z + a0.w*zj0[0].w
            + a1.x*zj0[1].x + a1.y*zj0[1].y + a1.z*zj0[1].z + a1.w*zj0[1].w
            + a2.x*zj0[2].x + a2.y*zj0[2].y + a2.z*zj0[2].z + a2.w*zj0[2].w
            + a3.x*zj0[3].x + a3.y*zj0[3].y + a3.z*zj0[3].z + a3.w*zj0[3].w;
        r.y = a0.x*zj1[0].x + a0.y*zj1[0].y + a0.z*zj1[0].z + a0.w*zj1[0].w
            + a1.x*zj1[1].x + a1.y*zj1[1].y + a1.z*zj1[1].z + a1.w*zj1[1].w
            + a2.x*zj1[2].x + a2.y*zj1[2].y + a2.z*zj1[2].z + a2.w*zj1[2].w
            + a3.x*zj1[3].x + a3.y*zj1[3].y + a3.z*zj1[3].z + a3.w*zj1[3].w;
        r.z = a0.x*zj2[0].x + a0.y*zj2[0].y + a0.z*zj2[0].z + a0.w*zj2[0].w
            + a1.x*zj2[1].x + a1.y*zj2[1].y + a1.z*zj2[1].z + a1.w*zj2[1].w
            + a2.x*zj2[2].x + a2.y*zj2[2].y + a2.z*zj2[2].z + a2.w*zj2[2].w
            + a3.x*zj2[3].x + a3.y*zj2[3].y + a3.z*zj2[3].z + a3.w*zj2[3].w;
        r.w = a0.x*zj3[0].x + a0.y*zj3[0].y + a0.z*zj3[0].z + a0.w*zj3[0].w
            + a1.x*zj3[1].x + a1.y*zj3[1].y + a1.z*zj3[1].z + a1.w*zj3[1].w
            + a2.x*zj3[2].x + a2.y*zj3[2].y + a2.z*zj3[2].z + a2.w*zj3[2].w
            + a3.x*zj3[3].x + a3.y*zj3[3].y + a3.z*zj3[3].z + a3.w*zj3[3].w;

        r.x = sigmoid_fast(r.x);
        r.y = sigmoid_fast(r.y);
        r.z = sigmoid_fast(r.z);
        r.w = sigmoid_fast(r.w);

        __builtin_nontemporal_store(
            r, (v4f*)(out + (size_t)(i0 + ii) * N_NODES + j0));
    }
}

// ---------------------------------------------------------------------------
// Launch: scratch (g0, g1, W12) lives inside the adj-recon region of d_out,
// which the decoder fully overwrites last. z accumulates directly into its
// final spot (tail of d_out). 5 dispatches total.
// ---------------------------------------------------------------------------
extern "C" void kernel_launch(void* const* d_in, const int* in_sizes, int n_in,
                              void* d_out, int out_size, void* d_ws, size_t ws_size,
                              hipStream_t stream) {
    const float* x  = (const float*)d_in[0];   // [N, 512]
    const float* W1 = (const float*)d_in[1];   // [512, 32]
    const float* W2 = (const float*)d_in[2];   // [32, 16]
    const int*   ei = (const int*)d_in[3];     // [2, E]
    const float* ew = (const float*)d_in[4];   // [E]
    const int E = in_sizes[3] / 2;
    const int* src = ei;
    const int* dst = ei + E;

    float* out = (float*)d_out;                              // [N, N]
    float* z   = out + (size_t)N_NODES * N_NODES;            // [N, 16] (final tail)

    // scratch inside the adj region (overwritten by decoder at the end)
    float* g0  = out;                          // N*16 floats @ 0
    float* g1  = g0 + N_NODES * LATENT;        // N*16 floats @ 160000
    float* W12 = g1 + N_NODES * LATENT;        // 512*16 floats @ 320000

    // fold weights: W12 = W1 @ W2
    w12_kernel<<<(F_IN * LATENT) / 256, 256, 0, stream>>>(W1, W2, W12);

    // g0 = x @ W12 (also zeroes g1 and z)
    gemm1_kernel<<<N_NODES / 16, 256, 0, stream>>>(x, W12, g0, g1, z);

    // g1 = A @ g0 ; z = A @ g1   (both at D=16)
    spmm_kernel<LATENT><<<(E * LATENT + 255) / 256, 256, 0, stream>>>(src, dst, ew, g0, g1, E);
    spmm_kernel<LATENT><<<(E * LATENT + 255) / 256, 256, 0, stream>>>(src, dst, ew, g1, z, E);

    // decoder: adj_recon = sigmoid(z @ z^T)
    dim3 dgrid((N_NODES / 4 + 255) / 256, (N_NODES + TI - 1) / TI);
    decoder_kernel<<<dgrid, 256, 0, stream>>>(z, out);
}